// Round 1
// baseline (252.655 us; speedup 1.0000x reference)
//
#include <hip/hip_runtime.h>

static constexpr int   N_NODES = 50000;
static constexpr int   N_EDGES = 600000;
static constexpr int   D       = 128;
static constexpr float ALPHA   = 0.1f;
static constexpr float BETA    = 0.22314355131420976f;  // log(1.25)
static constexpr float OMB     = 1.0f - BETA;           // (1-beta)

static constexpr int SCAN_TPB    = 256;
static constexpr int SCAN_BLOCKS = (N_NODES + SCAN_TPB - 1) / SCAN_TPB;  // 196

// ---------------- degree histogram (int atomics) ----------------
__global__ void deg_kernel(const int* __restrict__ dst, int* __restrict__ deg) {
    int e = blockIdx.x * blockDim.x + threadIdx.x;
    if (e < N_EDGES) atomicAdd(&deg[dst[e]], 1);
}

// ---------------- single-kernel scan ----------------
// Each block redundantly computes its global offset by summing deg[0..blockStart)
// (coalesced, L2-resident: total extra reads ~19 MB across grid — trivial),
// then does its block-local inclusive scan. Replaces the old
// partial/scanblock/finalscan 3-kernel chain (saves 2 launches + 2 bubbles).
__global__ __launch_bounds__(SCAN_TPB) void scan_kernel(
    const int* __restrict__ deg,
    int* __restrict__ row_start, int* __restrict__ cursor, float* __restrict__ norm) {
    __shared__ int sh[SCAN_TPB];
    const int t = threadIdx.x;
    const int i = blockIdx.x * SCAN_TPB + t;
    const int blockStart = blockIdx.x * SCAN_TPB;

    // 1) cross-block prefix: sum deg[0..blockStart)
    int pre = 0;
    for (int k = t; k < blockStart; k += SCAN_TPB) pre += deg[k];
    sh[t] = pre;
    __syncthreads();
    for (int off = SCAN_TPB / 2; off > 0; off >>= 1) {
        if (t < off) sh[t] += sh[t + off];
        __syncthreads();
    }
    const int blockOff = sh[0];
    __syncthreads();

    // 2) block-local inclusive scan (Hillis-Steele)
    int d = (i < N_NODES) ? deg[i] : 0;
    sh[t] = d;
    __syncthreads();
    for (int off = 1; off < SCAN_TPB; off <<= 1) {
        int u = (t >= off) ? sh[t - off] : 0;
        __syncthreads();
        sh[t] += u;
        __syncthreads();
    }
    if (i < N_NODES) {
        int pos = blockOff + sh[t] - d;   // exclusive prefix
        row_start[i] = pos;
        cursor[i]    = pos;
        norm[i]      = rsqrtf(fmaxf((float)d, 1.0f));
    }
}

// ---------------- CSR fill: csr[pos] = src, pos = cursor[dst]++ ----------------
__global__ void fill_kernel(const int* __restrict__ src, const int* __restrict__ dst,
                            int* __restrict__ cursor, int* __restrict__ csr) {
    int e = blockIdx.x * blockDim.x + threadIdx.x;
    if (e < N_EDGES) {
        int d   = dst[e];
        int pos = atomicAdd(&cursor[d], 1);
        if (pos >= 0 && pos < N_EDGES) csr[pos] = src[e];  // defensive bound
    }
}

// ---------------- gather: agg[n] = sum_{e: dst=n} feat[src_e] * norm[src_e] ----------------
// One wave (64 lanes) per node, split into two 32-lane halves.
// Each half owns a DIFFERENT edge (float4 = 16 B/lane over 32 lanes = 512 B row),
// 4 pairs = 8 edges in flight in the main loop. Halves combined at the end with
// a single cross-lane __shfl_xor(…,32). vs previous float2/4-edge version:
// half the load instructions per byte, 2x memory-level parallelism.
__global__ __launch_bounds__(256) void gather_kernel(
    const float* __restrict__ feat, const int* __restrict__ csr,
    const int* __restrict__ row_start, const int* __restrict__ deg,
    const float* __restrict__ norm, float* __restrict__ agg) {
    const int node = blockIdx.x * 4 + (threadIdx.x >> 6);   // grid*4 == N_NODES exactly
    const int lane = threadIdx.x & 63;
    const int half = lane >> 5;     // which edge of the pair this half handles
    const int l32  = lane & 31;     // column group: float4 at col l32*4
    const int base = row_start[node];
    const int cnt  = deg[node];
    const float* __restrict__ fcol = feat + (size_t)l32 * 4;

    float4 acc = make_float4(0.f, 0.f, 0.f, 0.f);
    int j = 0;
    for (; j + 8 <= cnt; j += 8) {
        const int e0 = base + j + half;
        int s0 = csr[e0];
        int s1 = csr[e0 + 2];
        int s2 = csr[e0 + 4];
        int s3 = csr[e0 + 6];
        float n0 = norm[s0], n1 = norm[s1], n2 = norm[s2], n3 = norm[s3];
        float4 v0 = *reinterpret_cast<const float4*>(fcol + (size_t)s0 * D);
        float4 v1 = *reinterpret_cast<const float4*>(fcol + (size_t)s1 * D);
        float4 v2 = *reinterpret_cast<const float4*>(fcol + (size_t)s2 * D);
        float4 v3 = *reinterpret_cast<const float4*>(fcol + (size_t)s3 * D);
        acc.x += v0.x * n0 + v1.x * n1 + v2.x * n2 + v3.x * n3;
        acc.y += v0.y * n0 + v1.y * n1 + v2.y * n2 + v3.y * n3;
        acc.z += v0.z * n0 + v1.z * n1 + v2.z * n2 + v3.z * n3;
        acc.w += v0.w * n0 + v1.w * n1 + v2.w * n2 + v3.w * n3;
    }
    for (; j < cnt; j += 2) {
        const int e = j + half;
        if (e < cnt) {
            int s = csr[base + e];
            float n = norm[s];
            float4 v = *reinterpret_cast<const float4*>(fcol + (size_t)s * D);
            acc.x += v.x * n;
            acc.y += v.y * n;
            acc.z += v.z * n;
            acc.w += v.w * n;
        }
    }
    // combine the two halves (lane i <-> lane i+32 hold the same columns)
    acc.x += __shfl_xor(acc.x, 32);
    acc.y += __shfl_xor(acc.y, 32);
    acc.z += __shfl_xor(acc.z, 32);
    acc.w += __shfl_xor(acc.w, 32);
    if (half == 0)
        *reinterpret_cast<float4*>(agg + (size_t)node * D + l32 * 4) = acc;
}

// ---------------- fused epilogue + GEMM, register-blocked 4x4 ----------------
// 32 rows/block; W streamed through LDS in FOUR 32-row chunks (16 KB buffer).
// LDS total 32 KB -> a real 4 blocks/CU (was 48 KB -> 3 blocks/CU).
// thread (t): cols c0..c0+3 (c0=(t&31)*4), rows r0..r0+3 (r0=(t>>5)*4).
// __launch_bounds__(256,4): cap 128 VGPR; #pragma unroll 1 on the k-loop
// prevents the full-unroll load-hoist that spilled to scratch in round 6.
static constexpr int TM = 32;   // rows per block

__global__ __launch_bounds__(256, 4) void final_kernel(
    const float* __restrict__ feat_0,
    const float* __restrict__ W,
    const float* __restrict__ bias,
    const float* __restrict__ norm,
    float* __restrict__ out)   // enters holding agg, exits holding rst
{
    __shared__ float w_sh[32 * D];   // 16 KB: quarter of W (32 k-rows)
    __shared__ float h_sh[TM * D];   // 16 KB

    const int t    = threadIdx.x;
    const int row0 = blockIdx.x * TM;

    // build h tile: TM*D = 4096 floats / 256 threads = 4 float4 each (coalesced)
    #pragma unroll
    for (int i = 0; i < 4; ++i) {
        int idx  = (i * 256 + t) * 4;     // 0..4092
        int r    = idx >> 7;
        int c    = idx & 127;
        int node = row0 + r;
        float4 h = make_float4(0.f, 0.f, 0.f, 0.f);
        if (node < N_NODES) {
            float nm = norm[node] * (1.0f - ALPHA);
            float4 a  = *reinterpret_cast<const float4*>(out    + (size_t)node * D + c);
            float4 f0 = *reinterpret_cast<const float4*>(feat_0 + (size_t)node * D + c);
            h.x = a.x * nm + f0.x * ALPHA;
            h.y = a.y * nm + f0.y * ALPHA;
            h.z = a.z * nm + f0.z * ALPHA;
            h.w = a.w * nm + f0.w * ALPHA;
        }
        *reinterpret_cast<float4*>(&h_sh[idx]) = h;
    }

    const int c0 = (t & 31) * 4;
    const int r0 = (t >> 5) * 4;

    float4 acc[4];   // acc[j] = row r0+j, cols c0..c0+3
    #pragma unroll
    for (int j = 0; j < 4; ++j) acc[j] = make_float4(0.f, 0.f, 0.f, 0.f);

    #pragma unroll 1
    for (int q = 0; q < 4; ++q) {
        __syncthreads();  // q=0: h_sh complete; q>0: w_sh no longer read
        // load 32 k-rows of W: 4096 floats / 256 threads = 4 float4 each (coalesced)
        #pragma unroll
        for (int i = 0; i < 4; ++i) {
            int idx = (i * 256 + t) * 4;  // 0..4092
            *reinterpret_cast<float4*>(&w_sh[idx]) =
                *reinterpret_cast<const float4*>(W + (size_t)q * 32 * D + idx);
        }
        __syncthreads();

        #pragma unroll 1
        for (int kk = 0; kk < 32; kk += 4) {
            const int kb = q * 32 + kk;
            // h fragments: broadcast reads (lanes 0-31 same addr)
            float4 hv[4];
            #pragma unroll
            for (int j = 0; j < 4; ++j)
                hv[j] = *reinterpret_cast<const float4*>(&h_sh[(r0 + j) * D + kb]);
            // w fragments: lane-contiguous b128
            float4 wv[4];
            #pragma unroll
            for (int ki = 0; ki < 4; ++ki)
                wv[ki] = *reinterpret_cast<const float4*>(&w_sh[(kk + ki) * D + c0]);
            #pragma unroll
            for (int ki = 0; ki < 4; ++ki) {
                #pragma unroll
                for (int j = 0; j < 4; ++j) {
                    float hj = (ki == 0) ? hv[j].x : (ki == 1) ? hv[j].y
                             : (ki == 2) ? hv[j].z : hv[j].w;
                    acc[j].x += hj * wv[ki].x;
                    acc[j].y += hj * wv[ki].y;
                    acc[j].z += hj * wv[ki].z;
                    acc[j].w += hj * wv[ki].w;
                }
            }
        }
    }

    const float4 b4 = *reinterpret_cast<const float4*>(bias + c0);
    #pragma unroll
    for (int j = 0; j < 4; ++j) {
        int node = row0 + r0 + j;
        if (node < N_NODES) {
            float4 h = *reinterpret_cast<const float4*>(&h_sh[(r0 + j) * D + c0]);
            float4 o;
            o.x = OMB * h.x + BETA * acc[j].x + b4.x;
            o.y = OMB * h.y + BETA * acc[j].y + b4.y;
            o.z = OMB * h.z + BETA * acc[j].z + b4.z;
            o.w = OMB * h.w + BETA * acc[j].w + b4.w;
            *reinterpret_cast<float4*>(out + (size_t)node * D + c0) = o;
        }
    }
}

extern "C" void kernel_launch(void* const* d_in, const int* in_sizes, int n_in,
                              void* d_out, int out_size, void* d_ws, size_t ws_size,
                              hipStream_t stream) {
    const float* feat   = (const float*)d_in[0];
    const float* feat_0 = (const float*)d_in[1];
    const float* W      = (const float*)d_in[2];
    const float* bias   = (const float*)d_in[3];
    const int*   src    = (const int*)d_in[4];
    const int*   dst    = (const int*)d_in[5];
    float*       out    = (float*)d_out;

    // workspace layout (blocksum slot retained for layout stability; unused)
    char* ws = (char*)d_ws;
    int*   deg       = (int*)ws;    ws += (size_t)N_NODES * 4;
    float* norm      = (float*)ws;  ws += (size_t)N_NODES * 4;
    int*   row_start = (int*)ws;    ws += (size_t)N_NODES * 4;
    int*   cursor    = (int*)ws;    ws += (size_t)N_NODES * 4;
    int*   blocksum  = (int*)ws;    ws += (size_t)SCAN_TPB * 4;
    int*   csr       = (int*)ws;    ws += (size_t)N_EDGES * 4;
    (void)blocksum;

    hipMemsetAsync(deg, 0, (size_t)N_NODES * sizeof(int), stream);

    deg_kernel<<<(N_EDGES + 255) / 256, 256, 0, stream>>>(dst, deg);
    scan_kernel<<<SCAN_BLOCKS, SCAN_TPB, 0, stream>>>(deg, row_start, cursor, norm);
    fill_kernel<<<(N_EDGES + 255) / 256, 256, 0, stream>>>(src, dst, cursor, csr);
    gather_kernel<<<(N_NODES + 3) / 4, 256, 0, stream>>>(feat, csr, row_start, deg, norm, out);
    final_kernel<<<(N_NODES + TM - 1) / TM, 256, 0, stream>>>(feat_0, W, bias, norm, out);
}